// Round 7
// baseline (72.605 us; speedup 1.0000x reference)
//
#include <hip/hip_runtime.h>

#define D    64
#define NROW 8192

typedef _Float16 f16x8 __attribute__((ext_vector_type(8)));
typedef float    f32x4 __attribute__((ext_vector_type(4)));

// ---------------------------------------------------------------------------
// RBF kernel, 256x256 output tile per block (halves HBM read traffic vs
// 128x128: the 268-MB write stream continuously evicts x/y from L2/LLC, so
// tile reads miss to HBM; read volume scales as 1/tile_dim).
// 512 threads = 8 waves as 4M x 2N. Per wave: 64 x-rows x 128 y-cols.
//   - y tile (256 rows) staged in LDS as f16 hi/lo split, XOR-swizzled
//     (identical row layout to the R3-verified kernel) + partial ysq.
//   - x fragments direct from global, split in-register; xsq via shfl_xor
//     (R3-verified, mt extended to 4).
//   - MFMA swapped operands (verified): A = y-frag, B = x-frag; lane's 4 acc
//     regs = 4 consecutive y-cols.
//   - dot = hi*hi + lo*hi + hi*lo; lo*lo dropped (absmax ~1e-28 vs 1.5e-20).
// ---------------------------------------------------------------------------
__global__ __launch_bounds__(512, 2) void rbf_big(const float* __restrict__ x,
                                                  const float* __restrict__ y,
                                                  float* __restrict__ out) {
    __shared__ __align__(16) char YH[32768];   // f16[256 rows][64 d], swizzled
    __shared__ __align__(16) char YL[32768];
    __shared__ float Ysq0[256];                // partial ||y||^2, d 0..31
    __shared__ float Ysq1[256];                // partial ||y||^2, d 32..63

    const int t    = threadIdx.x;
    const int col0 = blockIdx.x * 256;   // y-col tile
    const int row0 = blockIdx.y * 256;   // x-row tile

    // ---- stage y tile: hi/lo split + partial squared norms ---------------
    // 512 threads / 256 rows = 2 threads/row, 32 d-elems each (same
    // per-thread work as the R3-verified stager).
    {
        const int r    = t & 255;
        const int half = t >> 8;                 // d-halves 0..31 / 32..63
        const int swz  = (r & 7) << 4;
        const float* yp = y + (size_t)(col0 + r) * D + half * 32;
        float ssq = 0.f;
#pragma unroll
        for (int it = 0; it < 4; ++it) {
            float4 b0 = *reinterpret_cast<const float4*>(yp + it * 8);
            float4 b1 = *reinterpret_cast<const float4*>(yp + it * 8 + 4);
            float v[8] = {b0.x, b0.y, b0.z, b0.w, b1.x, b1.y, b1.z, b1.w};
            f16x8 h, l;
#pragma unroll
            for (int j = 0; j < 8; ++j) {
                _Float16 hh = (_Float16)v[j];
                h[j] = hh;
                l[j] = (_Float16)(v[j] - (float)hh);
                ssq  = fmaf(v[j], v[j], ssq);
            }
            const int off = r * 128 + ((half * 64 + it * 16) ^ swz);
            *reinterpret_cast<f16x8*>(YH + off) = h;
            *reinterpret_cast<f16x8*>(YL + off) = l;
        }
        if (half == 0) Ysq0[r] = ssq; else Ysq1[r] = ssq;
    }

    // ---- x fragments direct from global, split in-register ---------------
    const int lane = t & 63;
    const int w    = t >> 6;        // wave 0..7
    const int wm   = w >> 1;        // 0..3 -> x-row strip wm*64
    const int wn   = w & 1;         // 0..1 -> y-col strip wn*128
    const int l15  = lane & 15;
    const int lg   = lane >> 4;     // k-slot group

    f16x8 xh[4][2], xl[4][2];       // [m sub-tile][k half]
    float xsq[4];
#pragma unroll
    for (int mt = 0; mt < 4; ++mt) {
        const float* xp = x + (size_t)(row0 + wm * 64 + mt * 16 + l15) * D + lg * 8;
        float s = 0.f;
#pragma unroll
        for (int kh = 0; kh < 2; ++kh) {
            float4 a0 = *reinterpret_cast<const float4*>(xp + kh * 32);
            float4 a1 = *reinterpret_cast<const float4*>(xp + kh * 32 + 4);
            float v[8] = {a0.x, a0.y, a0.z, a0.w, a1.x, a1.y, a1.z, a1.w};
#pragma unroll
            for (int j = 0; j < 8; ++j) {
                _Float16 hh = (_Float16)v[j];
                xh[mt][kh][j] = hh;
                xl[mt][kh][j] = (_Float16)(v[j] - (float)hh);
                s = fmaf(v[j], v[j], s);
            }
        }
        s += __shfl_xor(s, 16);
        s += __shfl_xor(s, 32);
        xsq[mt] = s;
    }
    __syncthreads();

    // ---- MFMA main: A = y (LDS), B = x (reg); 192 MFMAs / wave -----------
    f32x4 acc[4][8];
#pragma unroll
    for (int mt = 0; mt < 4; ++mt)
#pragma unroll
        for (int nt = 0; nt < 8; ++nt) acc[mt][nt] = (f32x4){0.f, 0.f, 0.f, 0.f};

    const int swzA = (l15 & 7) << 4;   // y-row & 7 == l15 & 7 (offsets %8==0)
#pragma unroll
    for (int kh = 0; kh < 2; ++kh) {
        const int dsw = (kh * 64 + lg * 16) ^ swzA;
#pragma unroll
        for (int nt = 0; nt < 8; ++nt) {
            const int aoff = (wn * 128 + nt * 16 + l15) * 128 + dsw;
            f16x8 yh = *reinterpret_cast<const f16x8*>(YH + aoff);
            f16x8 yl = *reinterpret_cast<const f16x8*>(YL + aoff);
#pragma unroll
            for (int mt = 0; mt < 4; ++mt) {
                acc[mt][nt] = __builtin_amdgcn_mfma_f32_16x16x32_f16(yh, xh[mt][kh], acc[mt][nt], 0, 0, 0);
                acc[mt][nt] = __builtin_amdgcn_mfma_f32_16x16x32_f16(yl, xh[mt][kh], acc[mt][nt], 0, 0, 0);
                acc[mt][nt] = __builtin_amdgcn_mfma_f32_16x16x32_f16(yh, xl[mt][kh], acc[mt][nt], 0, 0, 0);
            }
        }
    }

    // ---- epilogue: dist^2 -> exp -> float4 stores (verified layout) ------
#pragma unroll
    for (int nt = 0; nt < 8; ++nt) {
        const int c = wn * 128 + nt * 16 + lg * 4;
        float4 p0 = *reinterpret_cast<const float4*>(&Ysq0[c]);
        float4 p1 = *reinterpret_cast<const float4*>(&Ysq1[c]);
        float ysqv[4] = {p0.x + p1.x, p0.y + p1.y, p0.z + p1.z, p0.w + p1.w};
#pragma unroll
        for (int mt = 0; mt < 4; ++mt) {
            const int rowg = row0 + wm * 64 + mt * 16 + l15;
            float e[4];
#pragma unroll
            for (int r = 0; r < 4; ++r) {
                float d2 = fmaf(-2.f, acc[mt][nt][r], xsq[mt] + ysqv[r]);
                d2 = fmaxf(d2, 0.f);
                e[r] = __expf(-d2);
            }
            *reinterpret_cast<float4*>(out + (size_t)rowg * NROW + col0 + c) =
                make_float4(e[0], e[1], e[2], e[3]);
        }
    }
}

extern "C" void kernel_launch(void* const* d_in, const int* in_sizes, int n_in,
                              void* d_out, int out_size, void* d_ws, size_t ws_size,
                              hipStream_t stream) {
    const float* x = (const float*)d_in[0];
    const float* y = (const float*)d_in[1];
    float* out = (float*)d_out;
    (void)d_ws; (void)ws_size;

    rbf_big<<<dim3(NROW / 256, NROW / 256), 512, 0, stream>>>(x, y, out);
}